// Round 7
// baseline (204.579 us; speedup 1.0000x reference)
//
#include <hip/hip_runtime.h>
#include <stdint.h>

typedef unsigned short u16;
typedef __attribute__((ext_vector_type(8))) short bf16x8;
typedef __attribute__((ext_vector_type(4))) float f32x4;
typedef __attribute__((ext_vector_type(16))) float f32x16;
typedef __attribute__((ext_vector_type(4))) u16 us4;
typedef __attribute__((ext_vector_type(8))) u16 us8;

// ---------- helpers ----------
__device__ __forceinline__ u16 f2bf(float f) {
  union { float f; unsigned u; } v; v.f = f;
  unsigned r = v.u + 0x7fffu + ((v.u >> 16) & 1u);   // RNE
  return (u16)(r >> 16);
}

__device__ __forceinline__ float bf2f(u16 b) {
  union { float f; unsigned u; } v; v.u = ((unsigned)b) << 16;
  return v.f;
}

// pack two positive f32 -> bf16x2 in one v_perm (round-to-nearest via +0x8000)
__device__ __forceinline__ unsigned pkbf(float a, float b) {
  union { float f; unsigned u; } x, y; x.f = a; y.f = b;
  return __builtin_amdgcn_perm(y.u + 0x8000u, x.u + 0x8000u, 0x07060302u);
}

__device__ __forceinline__ float fast_exp2(float x) {
#if __has_builtin(__builtin_amdgcn_exp2f)
  return __builtin_amdgcn_exp2f(x);
#else
  return exp2f(x);
#endif
}

__device__ __forceinline__ void gld16(const void* g, void* l) {
  __builtin_amdgcn_global_load_lds(
      (const __attribute__((address_space(1))) void*)g,
      (__attribute__((address_space(3))) void*)l, 16, 0, 0);
}

// ---------- prep (merged): cvt x -> bf16; transpose-convert both W ----------
__global__ void prep_kernel(const float* __restrict__ x, u16* __restrict__ Xb,
                            const float* __restrict__ Wqkv, u16* __restrict__ Wqkt,
                            const float* __restrict__ Wproj, u16* __restrict__ Wpt) {
  __shared__ u16 tile[32][33];
  const int blk = blockIdx.x;
  if (blk < 4096) {
    const int i = blk * 256 + threadIdx.x;
    f32x4 v = ((const f32x4*)x)[i];
    us4 r;
#pragma unroll
    for (int j = 0; j < 4; ++j) r[j] = f2bf(v[j]);
    ((us4*)Xb)[i] = r;
    return;
  }
  const float* in;
  u16* out;
  int R, C, t;
  if (blk < 7168) { in = Wqkv; out = Wqkt; R = 1024; C = 3072; t = blk - 4096; }
  else            { in = Wproj; out = Wpt; R = 1024; C = 1024; t = blk - 7168; }
  const int gx = (C == 3072) ? (t % 96) : (t % 32);
  const int gy = (C == 3072) ? (t / 96) : (t / 32);
  const int tx = threadIdx.x & 31, ty = threadIdx.x >> 5;
  const int c0 = gx * 32, r0 = gy * 32;
#pragma unroll
  for (int j = 0; j < 4; ++j)
    tile[ty + j * 8][tx] = f2bf(in[(size_t)(r0 + ty + j * 8) * C + c0 + tx]);
  __syncthreads();
#pragma unroll
  for (int j = 0; j < 4; ++j)
    out[(size_t)(c0 + ty + j * 8) * R + r0 + tx] = tile[tx][ty + j * 8];
}

// ---------- QKV GEMM: [4096,1024]bf16 @ [3072,1024]bf16^T + bias ----------
// (unchanged from r6 — proven) Q pre-scaled by 0.125*log2(e).
__global__ __launch_bounds__(256) void qkv_gemm_kernel(
    const u16* __restrict__ A, const u16* __restrict__ Bt, const float* __restrict__ bias,
    u16* __restrict__ Qb, u16* __restrict__ Kb, u16* __restrict__ Vtb) {
  __shared__ u16 sm[17408];
  u16* As = sm;
  u16* Bs = sm + 4096;
  const int tid = threadIdx.x;
  const int w = tid >> 6, l = tid & 63, quad = l >> 4, lanelo = l & 15;
  const int wr = w >> 1, wc = w & 1;
  const int flat = blockIdx.x + 32 * blockIdx.y;
  const int xcd = flat & 7, lid = flat >> 3;
  const long m0 = (long)((xcd >> 1) * 8 + (lid & 7)) * 128;
  const long n0 = (long)((xcd & 1) * 12 + (lid >> 3)) * 128;

  f32x4 acc[4][4];
#pragma unroll
  for (int i = 0; i < 4; ++i)
#pragma unroll
    for (int j = 0; j < 4; ++j) acc[i][j] = (f32x4){0.f, 0.f, 0.f, 0.f};

  const u16* ag = A + (m0 + w * 32 + (l >> 2)) * 1024 + (l & 3) * 8;
  const u16* bg = Bt + (n0 + w * 32 + (l >> 2)) * 1024 + (l & 3) * 8;
  u16* asl = As + w * 1024;
  u16* bsl = Bs + w * 1024;

  for (int kt = 0; kt < 32; ++kt) {
    const int ko = kt * 32;
    gld16(ag + ko, asl);
    gld16(ag + 16 * 1024 + ko, asl + 512);
    gld16(bg + ko, bsl);
    gld16(bg + 16 * 1024 + ko, bsl + 512);
    __syncthreads();
    bf16x8 af[4], bf[4];
#pragma unroll
    for (int mt = 0; mt < 4; ++mt)
      af[mt] = *(const bf16x8*)(As + (wr * 64 + mt * 16 + lanelo) * 32 + quad * 8);
#pragma unroll
    for (int nt = 0; nt < 4; ++nt)
      bf[nt] = *(const bf16x8*)(Bs + (wc * 64 + nt * 16 + lanelo) * 32 + quad * 8);
#pragma unroll
    for (int mt = 0; mt < 4; ++mt)
#pragma unroll
      for (int nt = 0; nt < 4; ++nt)
        acc[mt][nt] = __builtin_amdgcn_mfma_f32_16x16x32_bf16(af[mt], bf[nt], acc[mt][nt], 0, 0, 0);
    __syncthreads();
  }

  const int t = (int)(n0 >> 10);
  const float scl = (t == 0) ? 0.18033688011112042f : 1.0f;

  float bias_v[4];
#pragma unroll
  for (int nt = 0; nt < 4; ++nt) bias_v[nt] = bias[n0 + wc * 64 + nt * 16 + lanelo];

  u16* Ct = sm;  // [128][136]
#pragma unroll
  for (int mt = 0; mt < 4; ++mt)
#pragma unroll
    for (int nt = 0; nt < 4; ++nt)
#pragma unroll
      for (int r = 0; r < 4; ++r)
        Ct[(wr * 64 + mt * 16 + quad * 4 + r) * 136 + wc * 64 + nt * 16 + lanelo] =
            f2bf((acc[mt][nt][r] + bias_v[nt]) * scl);
  __syncthreads();

  const int b = (int)(m0 >> 11);
  const int s0 = (int)(m0 & 2047);
  const int h0 = (int)((n0 & 1023) >> 6);

  if (t < 2) {
    u16* dst = (t == 0) ? Qb : Kb;
#pragma unroll
    for (int p = 0; p < 8; ++p) {
      const int hh = p >> 2;
      const int sl = (p & 3) * 32 + (tid >> 3);
      const int c8 = tid & 7;
      us8 v = *(const us8*)(Ct + sl * 136 + hh * 64 + c8 * 8);
      const int pos = (c8 + sl) & 7;
      const size_t off = ((size_t)((b * 16 + h0 + hh) * 2048 + s0 + sl)) * 64 + pos * 8;
      *(us8*)(dst + off) = v;
    }
  } else {
#pragma unroll
    for (int p = 0; p < 8; ++p) {
      const int hh = p >> 2;
      const int dl = (p & 3) * 16 + (tid >> 4);
      const int c16 = tid & 15;
      us8 v;
#pragma unroll
      for (int j = 0; j < 8; ++j) v[j] = Ct[(c16 * 8 + j) * 136 + hh * 64 + dl];
      const int pos = (c16 + dl) & 15;
      const size_t off = ((size_t)((b * 16 + h0 + hh) * 64 + dl)) * 2048 + s0 + pos * 8;
      *(us8*)(Vtb + off) = v;
    }
  }
}

// ---------- flash attention: 32x32x16, z=2, DOUBLE-BUFFERED, no P exchange ----------
// PV k-slot permutation: slot (hi,j) of MFMA t maps to key (r&3)+8*(r>>2)+4*hi
// (r=t*8+j) — exactly the lane's own S^T C-regs, so the A-fragment is L[4t..4t+3]
// directly (zero cross-lane ops); V B-fragment = two b64 LDS reads per (t,n).
__global__ __launch_bounds__(256, 4) void attn_kernel(
    const u16* __restrict__ Qb, const u16* __restrict__ Kb,
    const u16* __restrict__ Vtb, u16* __restrict__ Op, float* __restrict__ lp) {
  __shared__ u16 Ks[2][8192];   // [key 128][dim 64]  8-chunk swizzled
  __shared__ u16 Vs[2][8192];   // [dim 64][key 128] 16-chunk swizzled
  const int tid = threadIdx.x;
  const int w = tid >> 6, l = tid & 63;
  const int m = l & 31, hi = l >> 5;
  const int fid = blockIdx.x;
  const int head = (fid & 7) + 8 * ((fid >> 3) & 3);   // 4 heads per XCD
  const int qt = (fid >> 5) & 15;
  const int z = fid >> 9;
  const u16* Qh = Qb + (size_t)head * 2048 * 64;
  const u16* Kh = Kb + (size_t)head * 2048 * 64;
  const u16* Vh = Vtb + (size_t)head * 64 * 2048;
  const int permaddr = (l ^ 32) << 2;

  const int qrow = qt * 128 + w * 32 + m;
  bf16x8 qf[4];
#pragma unroll
  for (int ks = 0; ks < 4; ++ks) {
    const int pos = (ks * 2 + hi + qrow) & 7;
    qf[ks] = *(const bf16x8*)(Qh + (size_t)qrow * 64 + pos * 8);
  }

  f32x16 o0, o1;
#pragma unroll
  for (int i = 0; i < 16; ++i) { o0[i] = 0.f; o1[i] = 0.f; }
  float sacc = 0.f;

  // prologue: stage tile 0 into buffer 0
  {
    const int kb = z * 8;
    const u16* kbase = Kh + (size_t)kb * 8192;
#pragma unroll
    for (int j = 0; j < 4; ++j) {
      const int i = w * 4 + j;
      gld16(kbase + i * 512 + l * 8, &Ks[0][i * 512]);
    }
#pragma unroll
    for (int j = 0; j < 4; ++j) {
      const int i = w * 4 + j;
      const int dd = i * 4 + (l >> 4);
      gld16(Vh + (size_t)dd * 2048 + kb * 128 + (l & 15) * 8, &Vs[0][i * 512]);
    }
  }

  for (int kt = 0; kt < 8; ++kt) {
    __syncthreads();   // drains buf[kt&1] loads (issued a full compute phase ago)
    if (kt < 7) {      // prefetch next tile into the other buffer
      const int kb = z * 8 + kt + 1;
      const int tb = (kt + 1) & 1;
      const u16* kbase = Kh + (size_t)kb * 8192;
#pragma unroll
      for (int j = 0; j < 4; ++j) {
        const int i = w * 4 + j;
        gld16(kbase + i * 512 + l * 8, &Ks[tb][i * 512]);
      }
#pragma unroll
      for (int j = 0; j < 4; ++j) {
        const int i = w * 4 + j;
        const int dd = i * 4 + (l >> 4);
        gld16(Vh + (size_t)dd * 2048 + kb * 128 + (l & 15) * 8, &Vs[tb][i * 512]);
      }
    }
    const u16* Kc = &Ks[kt & 1][0];
    const u16* Vc = &Vs[kt & 1][0];

#pragma unroll
    for (int g = 0; g < 4; ++g) {
      f32x16 st;
#pragma unroll
      for (int i = 0; i < 16; ++i) st[i] = 0.f;
      const int key = g * 32 + m;
#pragma unroll
      for (int ks = 0; ks < 4; ++ks) {
        const int pos = (ks * 2 + hi + key) & 7;
        bf16x8 kf = *(const bf16x8*)(&Kc[key * 64 + pos * 8]);
        st = __builtin_amdgcn_mfma_f32_32x32x16_bf16(kf, qf[ks], st, 0, 0, 0);
      }

      float p[16];
#pragma unroll
      for (int r = 0; r < 16; ++r) p[r] = fast_exp2(st[r]);
#pragma unroll
      for (int r = 0; r < 16; ++r) sacc += p[r];

      unsigned L[8];
#pragma unroll
      for (int q4 = 0; q4 < 4; ++q4) {
        L[2 * q4] = pkbf(p[4 * q4], p[4 * q4 + 1]);
        L[2 * q4 + 1] = pkbf(p[4 * q4 + 2], p[4 * q4 + 3]);
      }

#pragma unroll
      for (int t = 0; t < 2; ++t) {
        union { unsigned u[4]; bf16x8 v; } af;
#pragma unroll
        for (int j = 0; j < 4; ++j) af.u[j] = L[4 * t + j];
        const int c0 = g * 4 + t * 2;
#pragma unroll
        for (int n = 0; n < 2; ++n) {
          const int d = n * 32 + m;
          const int pos0 = (c0 + d) & 15;
          const int pos1 = (c0 + 1 + d) & 15;
          union { us4 q[2]; bf16x8 v; } vf;
          vf.q[0] = *(const us4*)(&Vc[d * 128 + pos0 * 8 + hi * 4]);
          vf.q[1] = *(const us4*)(&Vc[d * 128 + pos1 * 8 + hi * 4]);
          if (n == 0) o0 = __builtin_amdgcn_mfma_f32_32x32x16_bf16(af.v, vf.v, o0, 0, 0, 0);
          else        o1 = __builtin_amdgcn_mfma_f32_32x32x16_bf16(af.v, vf.v, o1, 0, 0, 0);
        }
      }
    }
  }

  // l = own half + partner half
  union { float f; int i; } sv; sv.f = sacc;
  union { float f; int i; } pv; pv.i = __builtin_amdgcn_ds_bpermute(permaddr, sv.i);
  const float ltot = sacc + pv.f;
  if (hi == 0)
    lp[(size_t)z * 65536 + (size_t)head * 2048 + qt * 128 + w * 32 + m] = ltot;

  // store unnormalized O partial (bf16) to Op[z][B,S,1024]
  const int b = head >> 4, h = head & 15;
  u16* Od = Op + (size_t)z * 4194304;
#pragma unroll
  for (int r = 0; r < 16; ++r) {
    const int qlocal = (r & 3) + 8 * (r >> 2) + 4 * hi;
    const size_t base =
        ((size_t)(b * 2048 + qt * 128 + w * 32 + qlocal)) * 1024 + h * 64;
    Od[base + m] = f2bf(o0[r]);
    Od[base + 32 + m] = f2bf(o1[r]);
  }
}

// ---------- proj GEMM with fused combine: A = (Op0+Op1)*linv staged via VALU ----------
// 128x64 tiles, 512 blocks. h = kt>>1 hoisted to an outer loop for linv reuse.
__global__ __launch_bounds__(256) void proj_gemm_kernel(
    const u16* __restrict__ Op, const float* __restrict__ lp,
    const u16* __restrict__ Bt, const float* __restrict__ bias,
    float* __restrict__ out) {
  __shared__ u16 sm[6144];   // As 128x32 (4096) + Bs 64x32 (2048)
  u16* As = sm;
  u16* Bs = sm + 4096;
  const int tid = threadIdx.x;
  const int w = tid >> 6, l = tid & 63, quad = l >> 4, lanelo = l & 15;
  const int wr = w >> 1, wc = w & 1;
  const int flat = blockIdx.x + 32 * blockIdx.y;       // 0..511
  const int xcd = flat & 7, lid = flat >> 3;
  const long m0 = (long)(xcd * 4 + (lid & 3)) * 128;
  const long n0 = (long)(lid >> 2) * 64;

  f32x4 acc[4][2];
#pragma unroll
  for (int i = 0; i < 4; ++i)
#pragma unroll
    for (int j = 0; j < 2; ++j) acc[i][j] = (f32x4){0.f, 0.f, 0.f, 0.f};

  const int r0 = (int)m0 + w * 32 + (l >> 2);   // lane's two A rows
  const int r1 = r0 + 16;
  const int c8 = (l & 3) * 8;
  const int bb = r0 >> 11;                       // batch (same for r0,r1)
  const int s0r = r0 & 2047, s1r = r1 & 2047;
  const u16* A0 = Op;
  const u16* A1 = Op + 4194304;

  const u16* bg = Bt + (n0 + w * 16 + (l >> 2)) * 1024 + (l & 3) * 8;
  u16* bsl = Bs + w * 512;
  u16* awr = As + w * 1024 + l * 8;

  for (int h = 0; h < 16; ++h) {
    const size_t lbase = (size_t)(bb * 16 + h) * 2048;
    const float li0 = 1.0f / (lp[lbase + s0r] + lp[65536 + lbase + s0r]);
    const float li1 = 1.0f / (lp[lbase + s1r] + lp[65536 + lbase + s1r]);
#pragma unroll
    for (int sub = 0; sub < 2; ++sub) {
      const int ko = (h * 2 + sub) * 32;
      us8 x0 = *(const us8*)(A0 + (size_t)r0 * 1024 + ko + c8);
      us8 y0 = *(const us8*)(A1 + (size_t)r0 * 1024 + ko + c8);
      us8 x1 = *(const us8*)(A0 + (size_t)r1 * 1024 + ko + c8);
      us8 y1 = *(const us8*)(A1 + (size_t)r1 * 1024 + ko + c8);
      gld16(bg + ko, bsl);
      us8 o0s, o1s;
#pragma unroll
      for (int j = 0; j < 8; ++j) {
        o0s[j] = f2bf((bf2f(x0[j]) + bf2f(y0[j])) * li0);
        o1s[j] = f2bf((bf2f(x1[j]) + bf2f(y1[j])) * li1);
      }
      *(us8*)(awr) = o0s;
      *(us8*)(awr + 512) = o1s;
      __syncthreads();
      bf16x8 af[4], bf[2];
#pragma unroll
      for (int mt = 0; mt < 4; ++mt)
        af[mt] = *(const bf16x8*)(As + (wr * 64 + mt * 16 + lanelo) * 32 + quad * 8);
#pragma unroll
      for (int nt = 0; nt < 2; ++nt)
        bf[nt] = *(const bf16x8*)(Bs + (wc * 32 + nt * 16 + lanelo) * 32 + quad * 8);
#pragma unroll
      for (int mt = 0; mt < 4; ++mt)
#pragma unroll
        for (int nt = 0; nt < 2; ++nt)
          acc[mt][nt] = __builtin_amdgcn_mfma_f32_16x16x32_bf16(af[mt], bf[nt], acc[mt][nt], 0, 0, 0);
      __syncthreads();
    }
  }

  float bias_v[2];
#pragma unroll
  for (int nt = 0; nt < 2; ++nt)
    bias_v[nt] = bias[n0 + wc * 32 + nt * 16 + lanelo];

#pragma unroll
  for (int mt = 0; mt < 4; ++mt)
#pragma unroll
    for (int nt = 0; nt < 2; ++nt)
#pragma unroll
      for (int r = 0; r < 4; ++r) {
        const size_t mm = m0 + wr * 64 + mt * 16 + quad * 4 + r;
        const size_t nn = n0 + wc * 32 + nt * 16 + lanelo;
        out[mm * 1024 + nn] = acc[mt][nt][r] + bias_v[nt];
      }
}

// ---------- launch ----------
extern "C" void kernel_launch(void* const* d_in, const int* in_sizes, int n_in,
                              void* d_out, int out_size, void* d_ws, size_t ws_size,
                              hipStream_t stream) {
  const float* x = (const float*)d_in[0];
  const float* Wqkv = (const float*)d_in[1];
  const float* bqkv = (const float*)d_in[2];
  const float* Wproj = (const float*)d_in[3];
  const float* bproj = (const float*)d_in[4];
  float* out = (float*)d_out;
  char* ws = (char*)d_ws;

  // workspace layout, lifetime-based aliasing:
  //  [ 0..8M)   Xb (dead after qkv) -> Op0 ; [8..16M) Wqkt (dead after qkv) -> Op1
  //  [24..32M)  Kb ; [32..40M) Vtb ; [40..42M) Wpt ; [42..42.5M) lp
  //  [16..24M)  Qb (dead after attn)
  u16* Xb   = (u16*)(ws);
  u16* Op   = (u16*)(ws);                 // Op0 @0, Op1 @ +4194304 elems
  u16* Wqkt = (u16*)(ws + 8388608);
  u16* Qb   = (u16*)(ws + 16777216);
  u16* Kb   = (u16*)(ws + 25165824);
  u16* Vtb  = (u16*)(ws + 33554432);
  u16* Wpt  = (u16*)(ws + 41943040);
  float* lp = (float*)(ws + 44040192);

  prep_kernel<<<8192, 256, 0, stream>>>(x, Xb, Wqkv, Wqkt, Wproj, Wpt);
  qkv_gemm_kernel<<<dim3(32, 24), 256, 0, stream>>>(Xb, Wqkt, bqkv, Qb, Kb, Vtb);
  attn_kernel<<<1024, 256, 0, stream>>>(Qb, Kb, Vtb, Op, lp);
  proj_gemm_kernel<<<dim3(32, 16), 256, 0, stream>>>(Op, lp, Wpt, bproj, out);
}

// Round 8
// 192.076 us; speedup vs baseline: 1.0651x; 1.0651x over previous
//
#include <hip/hip_runtime.h>
#include <stdint.h>

typedef unsigned short u16;
typedef __attribute__((ext_vector_type(8))) short bf16x8;
typedef __attribute__((ext_vector_type(4))) float f32x4;
typedef __attribute__((ext_vector_type(16))) float f32x16;
typedef __attribute__((ext_vector_type(4))) u16 us4;
typedef __attribute__((ext_vector_type(8))) u16 us8;

// ---------- helpers ----------
__device__ __forceinline__ u16 f2bf(float f) {
  union { float f; unsigned u; } v; v.f = f;
  unsigned r = v.u + 0x7fffu + ((v.u >> 16) & 1u);   // RNE
  return (u16)(r >> 16);
}

__device__ __forceinline__ float bf2f(u16 b) {
  union { float f; unsigned u; } v; v.u = ((unsigned)b) << 16;
  return v.f;
}

// pack two positive f32 -> bf16x2 in one v_perm (round-to-nearest via +0x8000)
__device__ __forceinline__ unsigned pkbf(float a, float b) {
  union { float f; unsigned u; } x, y; x.f = a; y.f = b;
  return __builtin_amdgcn_perm(y.u + 0x8000u, x.u + 0x8000u, 0x07060302u);
}

__device__ __forceinline__ float fast_exp2(float x) {
#if __has_builtin(__builtin_amdgcn_exp2f)
  return __builtin_amdgcn_exp2f(x);
#else
  return exp2f(x);
#endif
}

__device__ __forceinline__ void gld16(const void* g, void* l) {
  __builtin_amdgcn_global_load_lds(
      (const __attribute__((address_space(1))) void*)g,
      (__attribute__((address_space(3))) void*)l, 16, 0, 0);
}

// ---------- prep (merged): cvt x -> bf16; transpose-convert both W ----------
__global__ void prep_kernel(const float* __restrict__ x, u16* __restrict__ Xb,
                            const float* __restrict__ Wqkv, u16* __restrict__ Wqkt,
                            const float* __restrict__ Wproj, u16* __restrict__ Wpt) {
  __shared__ u16 tile[32][33];
  const int blk = blockIdx.x;
  if (blk < 4096) {
    const int i = blk * 256 + threadIdx.x;
    f32x4 v = ((const f32x4*)x)[i];
    us4 r;
#pragma unroll
    for (int j = 0; j < 4; ++j) r[j] = f2bf(v[j]);
    ((us4*)Xb)[i] = r;
    return;
  }
  const float* in;
  u16* out;
  int R, C, t;
  if (blk < 7168) { in = Wqkv; out = Wqkt; R = 1024; C = 3072; t = blk - 4096; }
  else            { in = Wproj; out = Wpt; R = 1024; C = 1024; t = blk - 7168; }
  const int gx = (C == 3072) ? (t % 96) : (t % 32);
  const int gy = (C == 3072) ? (t / 96) : (t / 32);
  const int tx = threadIdx.x & 31, ty = threadIdx.x >> 5;
  const int c0 = gx * 32, r0 = gy * 32;
#pragma unroll
  for (int j = 0; j < 4; ++j)
    tile[ty + j * 8][tx] = f2bf(in[(size_t)(r0 + ty + j * 8) * C + c0 + tx]);
  __syncthreads();
#pragma unroll
  for (int j = 0; j < 4; ++j)
    out[(size_t)(c0 + ty + j * 8) * R + r0 + tx] = tile[tx][ty + j * 8];
}

// ---------- QKV GEMM: [4096,1024]bf16 @ [3072,1024]bf16^T + bias ----------
// (r6 verbatim — proven) Q pre-scaled by 0.125*log2(e).
__global__ __launch_bounds__(256) void qkv_gemm_kernel(
    const u16* __restrict__ A, const u16* __restrict__ Bt, const float* __restrict__ bias,
    u16* __restrict__ Qb, u16* __restrict__ Kb, u16* __restrict__ Vtb) {
  __shared__ u16 sm[17408];
  u16* As = sm;
  u16* Bs = sm + 4096;
  const int tid = threadIdx.x;
  const int w = tid >> 6, l = tid & 63, quad = l >> 4, lanelo = l & 15;
  const int wr = w >> 1, wc = w & 1;
  const int flat = blockIdx.x + 32 * blockIdx.y;
  const int xcd = flat & 7, lid = flat >> 3;
  const long m0 = (long)((xcd >> 1) * 8 + (lid & 7)) * 128;
  const long n0 = (long)((xcd & 1) * 12 + (lid >> 3)) * 128;

  f32x4 acc[4][4];
#pragma unroll
  for (int i = 0; i < 4; ++i)
#pragma unroll
    for (int j = 0; j < 4; ++j) acc[i][j] = (f32x4){0.f, 0.f, 0.f, 0.f};

  const u16* ag = A + (m0 + w * 32 + (l >> 2)) * 1024 + (l & 3) * 8;
  const u16* bg = Bt + (n0 + w * 32 + (l >> 2)) * 1024 + (l & 3) * 8;
  u16* asl = As + w * 1024;
  u16* bsl = Bs + w * 1024;

  for (int kt = 0; kt < 32; ++kt) {
    const int ko = kt * 32;
    gld16(ag + ko, asl);
    gld16(ag + 16 * 1024 + ko, asl + 512);
    gld16(bg + ko, bsl);
    gld16(bg + 16 * 1024 + ko, bsl + 512);
    __syncthreads();
    bf16x8 af[4], bf[4];
#pragma unroll
    for (int mt = 0; mt < 4; ++mt)
      af[mt] = *(const bf16x8*)(As + (wr * 64 + mt * 16 + lanelo) * 32 + quad * 8);
#pragma unroll
    for (int nt = 0; nt < 4; ++nt)
      bf[nt] = *(const bf16x8*)(Bs + (wc * 64 + nt * 16 + lanelo) * 32 + quad * 8);
#pragma unroll
    for (int mt = 0; mt < 4; ++mt)
#pragma unroll
      for (int nt = 0; nt < 4; ++nt)
        acc[mt][nt] = __builtin_amdgcn_mfma_f32_16x16x32_bf16(af[mt], bf[nt], acc[mt][nt], 0, 0, 0);
    __syncthreads();
  }

  const int t = (int)(n0 >> 10);
  const float scl = (t == 0) ? 0.18033688011112042f : 1.0f;

  float bias_v[4];
#pragma unroll
  for (int nt = 0; nt < 4; ++nt) bias_v[nt] = bias[n0 + wc * 64 + nt * 16 + lanelo];

  u16* Ct = sm;  // [128][136]
#pragma unroll
  for (int mt = 0; mt < 4; ++mt)
#pragma unroll
    for (int nt = 0; nt < 4; ++nt)
#pragma unroll
      for (int r = 0; r < 4; ++r)
        Ct[(wr * 64 + mt * 16 + quad * 4 + r) * 136 + wc * 64 + nt * 16 + lanelo] =
            f2bf((acc[mt][nt][r] + bias_v[nt]) * scl);
  __syncthreads();

  const int b = (int)(m0 >> 11);
  const int s0 = (int)(m0 & 2047);
  const int h0 = (int)((n0 & 1023) >> 6);

  if (t < 2) {
    u16* dst = (t == 0) ? Qb : Kb;
#pragma unroll
    for (int p = 0; p < 8; ++p) {
      const int hh = p >> 2;
      const int sl = (p & 3) * 32 + (tid >> 3);
      const int c8 = tid & 7;
      us8 v = *(const us8*)(Ct + sl * 136 + hh * 64 + c8 * 8);
      const int pos = (c8 + sl) & 7;
      const size_t off = ((size_t)((b * 16 + h0 + hh) * 2048 + s0 + sl)) * 64 + pos * 8;
      *(us8*)(dst + off) = v;
    }
  } else {
#pragma unroll
    for (int p = 0; p < 8; ++p) {
      const int hh = p >> 2;
      const int dl = (p & 3) * 16 + (tid >> 4);
      const int c16 = tid & 15;
      us8 v;
#pragma unroll
      for (int j = 0; j < 8; ++j) v[j] = Ct[(c16 * 8 + j) * 136 + hh * 64 + dl];
      const int pos = (c16 + dl) & 15;
      const size_t off = ((size_t)((b * 16 + h0 + hh) * 64 + dl)) * 2048 + s0 + pos * 8;
      *(us8*)(Vtb + off) = v;
    }
  }
}

// ---------- flash attention: 128q x 64-key subtiles, DOUBLE-BUFFERED @ 32 KiB ----------
// Same reuse/barrier count as r6 (128q tile, 16 barriers), but each barrier drains
// loads issued a full compute phase earlier. K/V buffers 4x8KB = 32 KiB total ->
// 4 blocks/CU kept. V staging gathers the global 128-key swizzle into a per-64-key
// swizzle via per-lane src addresses (LDS dest stays lane-linear per gld16 rules).
// Exchange/rowsum/epilogue identical to r6 (proven).
__global__ __launch_bounds__(256, 4) void attn_kernel(
    const u16* __restrict__ Qb, const u16* __restrict__ Kb,
    const u16* __restrict__ Vtb, u16* __restrict__ Op, float* __restrict__ lp) {
  __shared__ u16 Ks[2][4096];   // [key 64][dim 64] row-swizzled (same as global)
  __shared__ u16 Vs[2][4096];   // [dim 64][key 64] chunk c8 at pos8=(c8+d)&7
  const int tid = threadIdx.x;
  const int w = tid >> 6, l = tid & 63;
  const int m = l & 31, hi = l >> 5;
  const int fid = blockIdx.x;
  const int head = (fid & 7) + 8 * ((fid >> 3) & 3);   // 4 heads per XCD
  const int qt = (fid >> 5) & 15;
  const int z = fid >> 9;
  const u16* Qh = Qb + (size_t)head * 2048 * 64;
  const u16* Kh = Kb + (size_t)head * 2048 * 64;
  const u16* Vh = Vtb + (size_t)head * 64 * 2048;
  const int permaddr = (l ^ 32) << 2;

  // Q fragments (valid as B-operand: same per-lane layout)
  const int qrow = qt * 128 + w * 32 + m;
  bf16x8 qf[4];
#pragma unroll
  for (int ks = 0; ks < 4; ++ks) {
    const int pos = (ks * 2 + hi + qrow) & 7;
    qf[ks] = *(const bf16x8*)(Qh + (size_t)qrow * 64 + pos * 8);
  }

  // staging lane constants
  const int kslot = w * 2;                 // wave's 2 K-instr slots
  const int d0 = w * 16 + (l >> 3);        // V: j=0 dim row (j=1 adds 8)
  const int pos8l = l & 7;
  const int c8st = (pos8l - d0) & 7;       // chunk held at this lane's LDS slot

  f32x16 o0, o1;
#pragma unroll
  for (int i = 0; i < 16; ++i) { o0[i] = 0.f; o1[i] = 0.f; }
  float sacc = 0.f;

  // prologue: stage tile 0 into buffer 0
  {
    const int kb = z * 1024;
    const int kb128 = z * 8;
#pragma unroll
    for (int j = 0; j < 2; ++j)
      gld16(Kh + (size_t)kb * 64 + (kslot + j) * 512 + l * 8,
            &Ks[0][(kslot + j) * 512 + l * 8]);
#pragma unroll
    for (int j = 0; j < 2; ++j) {
      const int d = d0 + j * 8;
      const int pos16 = (c8st + d) & 15;   // halfsel = 0 for tile 0
      gld16(Vh + (size_t)d * 2048 + kb128 * 128 + pos16 * 8,
            &Vs[0][(kslot + j) * 512 + l * 8]);
    }
  }

  for (int t = 0; t < 16; ++t) {
    __syncthreads();   // drains buf[t&1] loads (issued a full compute phase ago)
    if (t < 15) {      // prefetch next 64-key tile into the other buffer
      const int tn = t + 1;
      const int tb = tn & 1;
      const int kb = z * 1024 + tn * 64;
      const int kb128 = z * 8 + (tn >> 1);
      const int hsel = (tn & 1) * 8;
#pragma unroll
      for (int j = 0; j < 2; ++j)
        gld16(Kh + (size_t)kb * 64 + (kslot + j) * 512 + l * 8,
              &Ks[tb][(kslot + j) * 512 + l * 8]);
#pragma unroll
      for (int j = 0; j < 2; ++j) {
        const int d = d0 + j * 8;
        const int pos16 = (hsel + c8st + d) & 15;
        gld16(Vh + (size_t)d * 2048 + kb128 * 128 + pos16 * 8,
              &Vs[tb][(kslot + j) * 512 + l * 8]);
      }
    }
    const u16* Kc = &Ks[t & 1][0];
    const u16* Vc = &Vs[t & 1][0];

#pragma unroll
    for (int g = 0; g < 2; ++g) {
      f32x16 st;
#pragma unroll
      for (int i = 0; i < 16; ++i) st[i] = 0.f;
      const int key = g * 32 + m;
#pragma unroll
      for (int ks = 0; ks < 4; ++ks) {
        const int pos = (ks * 2 + hi + key) & 7;
        bf16x8 kf = *(const bf16x8*)(&Kc[key * 64 + pos * 8]);
        st = __builtin_amdgcn_mfma_f32_32x32x16_bf16(kf, qf[ks], st, 0, 0, 0);
      }

      float p[16];
#pragma unroll
      for (int r = 0; r < 16; ++r) p[r] = fast_exp2(st[r]);
#pragma unroll
      for (int r = 0; r < 16; ++r) sacc += p[r];

      unsigned L[8];
#pragma unroll
      for (int q4 = 0; q4 < 4; ++q4) {
        L[2 * q4] = pkbf(p[4 * q4], p[4 * q4 + 1]);
        L[2 * q4 + 1] = pkbf(p[4 * q4 + 2], p[4 * q4 + 3]);
      }

#pragma unroll
      for (int s = 0; s < 2; ++s) {
        const unsigned a0 = L[4 * s], a1 = L[4 * s + 1];     // quad 2s
        const unsigned b0 = L[4 * s + 2], b1 = L[4 * s + 3]; // quad 2s+1
        const unsigned s0 = hi ? a0 : b0;
        const unsigned s1 = hi ? a1 : b1;
        const unsigned r0 = (unsigned)__builtin_amdgcn_ds_bpermute(permaddr, (int)s0);
        const unsigned r1 = (unsigned)__builtin_amdgcn_ds_bpermute(permaddr, (int)s1);
        int4 fd;
        fd.x = (int)(hi ? r0 : a0);
        fd.y = (int)(hi ? r1 : a1);
        fd.z = (int)(hi ? b0 : r0);
        fd.w = (int)(hi ? b1 : r1);
        union { int4 i; bf16x8 v; } pu; pu.i = fd;
        const int c = g * 4 + s * 2 + hi;   // key chunk 0..7 for V B-operand
#pragma unroll
        for (int n = 0; n < 2; ++n) {
          const int d = n * 32 + m;
          const int pos = (c + d) & 7;
          bf16x8 vf = *(const bf16x8*)(&Vc[d * 64 + pos * 8]);
          if (n == 0) o0 = __builtin_amdgcn_mfma_f32_32x32x16_bf16(pu.v, vf, o0, 0, 0, 0);
          else        o1 = __builtin_amdgcn_mfma_f32_32x32x16_bf16(pu.v, vf, o1, 0, 0, 0);
        }
      }
    }
  }

  // l = own half + partner half
  union { float f; int i; } sv; sv.f = sacc;
  union { float f; int i; } pv; pv.i = __builtin_amdgcn_ds_bpermute(permaddr, sv.i);
  const float ltot = sacc + pv.f;
  if (hi == 0)
    lp[(size_t)z * 65536 + (size_t)head * 2048 + qt * 128 + w * 32 + m] = ltot;

  // store unnormalized O partial (bf16) to Op[z][B,S,1024]
  const int b = head >> 4, h = head & 15;
  u16* Od = Op + (size_t)z * 4194304;
#pragma unroll
  for (int r = 0; r < 16; ++r) {
    const int qlocal = (r & 3) + 8 * (r >> 2) + 4 * hi;
    const size_t base =
        ((size_t)(b * 2048 + qt * 128 + w * 32 + qlocal)) * 1024 + h * 64;
    Od[base + m] = f2bf(o0[r]);
    Od[base + 32 + m] = f2bf(o1[r]);
  }
}

// ---------- combine: Ob = (Op0 + Op1) / (l0 + l1), bf16 out ----------
__global__ __launch_bounds__(128) void combine_kernel(
    const u16* __restrict__ Op, const float* __restrict__ lp, u16* __restrict__ Ob) {
  const int r = blockIdx.x;          // 0..4095
  const int tid = threadIdx.x;       // 0..127
  const int col = tid * 8;
  const int b = r >> 11, s = r & 2047, h = col >> 6;
  const size_t li = (size_t)(b * 16 + h) * 2048 + s;
  const float linv = 1.0f / (lp[li] + lp[65536 + li]);
  us8 v0 = *(const us8*)(Op + (size_t)r * 1024 + col);
  us8 v1 = *(const us8*)(Op + 4194304 + (size_t)r * 1024 + col);
  us8 o;
#pragma unroll
  for (int j = 0; j < 8; ++j)
    o[j] = f2bf((bf2f(v0[j]) + bf2f(v1[j])) * linv);
  *(us8*)(Ob + (size_t)r * 1024 + col) = o;
}

// ---------- proj GEMM: 128x64 tiles, 512 blocks (2/CU), plain stores ----------
__global__ __launch_bounds__(256) void proj_gemm_kernel(
    const u16* __restrict__ A, const u16* __restrict__ Bt,
    const float* __restrict__ bias, float* __restrict__ out) {
  __shared__ u16 sm[6144];   // As 128x32 (4096) + Bs 64x32 (2048)
  u16* As = sm;
  u16* Bs = sm + 4096;
  const int tid = threadIdx.x;
  const int w = tid >> 6, l = tid & 63, quad = l >> 4, lanelo = l & 15;
  const int wr = w >> 1, wc = w & 1;
  const int flat = blockIdx.x + 32 * blockIdx.y;       // 0..511
  const int xcd = flat & 7, lid = flat >> 3;
  const long m0 = (long)(xcd * 4 + (lid & 3)) * 128;
  const long n0 = (long)(lid >> 2) * 64;

  f32x4 acc[4][2];
#pragma unroll
  for (int i = 0; i < 4; ++i)
#pragma unroll
    for (int j = 0; j < 2; ++j) acc[i][j] = (f32x4){0.f, 0.f, 0.f, 0.f};

  const u16* ag = A + (m0 + w * 32 + (l >> 2)) * 1024 + (l & 3) * 8;
  const u16* bg = Bt + (n0 + w * 16 + (l >> 2)) * 1024 + (l & 3) * 8;
  u16* asl = As + w * 1024;
  u16* bsl = Bs + w * 512;

  for (int kt = 0; kt < 32; ++kt) {
    const int ko = kt * 32;
    gld16(ag + ko, asl);
    gld16(ag + 16 * 1024 + ko, asl + 512);
    gld16(bg + ko, bsl);
    __syncthreads();
    bf16x8 af[4], bf[2];
#pragma unroll
    for (int mt = 0; mt < 4; ++mt)
      af[mt] = *(const bf16x8*)(As + (wr * 64 + mt * 16 + lanelo) * 32 + quad * 8);
#pragma unroll
    for (int nt = 0; nt < 2; ++nt)
      bf[nt] = *(const bf16x8*)(Bs + (wc * 32 + nt * 16 + lanelo) * 32 + quad * 8);
#pragma unroll
    for (int mt = 0; mt < 4; ++mt)
#pragma unroll
      for (int nt = 0; nt < 2; ++nt)
        acc[mt][nt] = __builtin_amdgcn_mfma_f32_16x16x32_bf16(af[mt], bf[nt], acc[mt][nt], 0, 0, 0);
    __syncthreads();
  }

  float bias_v[2];
#pragma unroll
  for (int nt = 0; nt < 2; ++nt)
    bias_v[nt] = bias[n0 + wc * 32 + nt * 16 + lanelo];

#pragma unroll
  for (int mt = 0; mt < 4; ++mt)
#pragma unroll
    for (int nt = 0; nt < 2; ++nt)
#pragma unroll
      for (int r = 0; r < 4; ++r) {
        const size_t mm = m0 + wr * 64 + mt * 16 + quad * 4 + r;
        const size_t nn = n0 + wc * 32 + nt * 16 + lanelo;
        out[mm * 1024 + nn] = acc[mt][nt][r] + bias_v[nt];
      }
}

// ---------- launch ----------
extern "C" void kernel_launch(void* const* d_in, const int* in_sizes, int n_in,
                              void* d_out, int out_size, void* d_ws, size_t ws_size,
                              hipStream_t stream) {
  const float* x = (const float*)d_in[0];
  const float* Wqkv = (const float*)d_in[1];
  const float* bqkv = (const float*)d_in[2];
  const float* Wproj = (const float*)d_in[3];
  const float* bproj = (const float*)d_in[4];
  float* out = (float*)d_out;
  char* ws = (char*)d_ws;

  // workspace layout, lifetime-based aliasing:
  //  [ 0..8M)   Xb (dead after qkv) -> Op0 ; [8..16M) Wqkt (dead after qkv) -> Op1
  //  [16..24M)  Qb (dead after attn) -> Ob ; [24..32M) Kb ; [32..40M) Vtb
  //  [40..42M)  Wpt ; [42..42.5M) lp
  u16* Xb   = (u16*)(ws);
  u16* Op   = (u16*)(ws);                 // Op0 @0, Op1 @ +4194304 elems
  u16* Wqkt = (u16*)(ws + 8388608);
  u16* Qb   = (u16*)(ws + 16777216);
  u16* Ob   = (u16*)(ws + 16777216);
  u16* Kb   = (u16*)(ws + 25165824);
  u16* Vtb  = (u16*)(ws + 33554432);
  u16* Wpt  = (u16*)(ws + 41943040);
  float* lp = (float*)(ws + 44040192);

  prep_kernel<<<8192, 256, 0, stream>>>(x, Xb, Wqkv, Wqkt, Wproj, Wpt);
  qkv_gemm_kernel<<<dim3(32, 24), 256, 0, stream>>>(Xb, Wqkt, bqkv, Qb, Kb, Vtb);
  attn_kernel<<<1024, 256, 0, stream>>>(Qb, Kb, Vtb, Op, lp);
  combine_kernel<<<4096, 128, 0, stream>>>(Op, lp, Ob);
  proj_gemm_kernel<<<dim3(32, 16), 256, 0, stream>>>(Ob, Wpt, bproj, out);
}

// Round 9
// 187.000 us; speedup vs baseline: 1.0940x; 1.0271x over previous
//
#include <hip/hip_runtime.h>
#include <stdint.h>

typedef unsigned short u16;
typedef __attribute__((ext_vector_type(8))) short bf16x8;
typedef __attribute__((ext_vector_type(4))) float f32x4;
typedef __attribute__((ext_vector_type(16))) float f32x16;
typedef __attribute__((ext_vector_type(4))) u16 us4;
typedef __attribute__((ext_vector_type(8))) u16 us8;

// ---------- helpers ----------
__device__ __forceinline__ u16 f2bf(float f) {
  union { float f; unsigned u; } v; v.f = f;
  unsigned r = v.u + 0x7fffu + ((v.u >> 16) & 1u);   // RNE
  return (u16)(r >> 16);
}

__device__ __forceinline__ float bf2f(u16 b) {
  union { float f; unsigned u; } v; v.u = ((unsigned)b) << 16;
  return v.f;
}

// pack two positive f32 -> bf16x2 in one v_perm (round-to-nearest via +0x8000)
__device__ __forceinline__ unsigned pkbf(float a, float b) {
  union { float f; unsigned u; } x, y; x.f = a; y.f = b;
  return __builtin_amdgcn_perm(y.u + 0x8000u, x.u + 0x8000u, 0x07060302u);
}

__device__ __forceinline__ float fast_exp2(float x) {
#if __has_builtin(__builtin_amdgcn_exp2f)
  return __builtin_amdgcn_exp2f(x);
#else
  return exp2f(x);
#endif
}

__device__ __forceinline__ void gld16(const void* g, void* l) {
  __builtin_amdgcn_global_load_lds(
      (const __attribute__((address_space(1))) void*)g,
      (__attribute__((address_space(3))) void*)l, 16, 0, 0);
}

// ---------- prep (merged): cvt x -> bf16; transpose-convert both W ----------
__global__ void prep_kernel(const float* __restrict__ x, u16* __restrict__ Xb,
                            const float* __restrict__ Wqkv, u16* __restrict__ Wqkt,
                            const float* __restrict__ Wproj, u16* __restrict__ Wpt) {
  __shared__ u16 tile[32][33];
  const int blk = blockIdx.x;
  if (blk < 4096) {
    const int i = blk * 256 + threadIdx.x;
    f32x4 v = ((const f32x4*)x)[i];
    us4 r;
#pragma unroll
    for (int j = 0; j < 4; ++j) r[j] = f2bf(v[j]);
    ((us4*)Xb)[i] = r;
    return;
  }
  const float* in;
  u16* out;
  int R, C, t;
  if (blk < 7168) { in = Wqkv; out = Wqkt; R = 1024; C = 3072; t = blk - 4096; }
  else            { in = Wproj; out = Wpt; R = 1024; C = 1024; t = blk - 7168; }
  const int gx = (C == 3072) ? (t % 96) : (t % 32);
  const int gy = (C == 3072) ? (t / 96) : (t / 32);
  const int tx = threadIdx.x & 31, ty = threadIdx.x >> 5;
  const int c0 = gx * 32, r0 = gy * 32;
#pragma unroll
  for (int j = 0; j < 4; ++j)
    tile[ty + j * 8][tx] = f2bf(in[(size_t)(r0 + ty + j * 8) * C + c0 + tx]);
  __syncthreads();
#pragma unroll
  for (int j = 0; j < 4; ++j)
    out[(size_t)(c0 + ty + j * 8) * R + r0 + tx] = tile[tx][ty + j * 8];
}

// ---------- QKV GEMM: [4096,1024]bf16 @ [3072,1024]bf16^T + bias ----------
// (r6 verbatim — proven) Q pre-scaled by 0.125*log2(e).
__global__ __launch_bounds__(256) void qkv_gemm_kernel(
    const u16* __restrict__ A, const u16* __restrict__ Bt, const float* __restrict__ bias,
    u16* __restrict__ Qb, u16* __restrict__ Kb, u16* __restrict__ Vtb) {
  __shared__ u16 sm[17408];
  u16* As = sm;
  u16* Bs = sm + 4096;
  const int tid = threadIdx.x;
  const int w = tid >> 6, l = tid & 63, quad = l >> 4, lanelo = l & 15;
  const int wr = w >> 1, wc = w & 1;
  const int flat = blockIdx.x + 32 * blockIdx.y;
  const int xcd = flat & 7, lid = flat >> 3;
  const long m0 = (long)((xcd >> 1) * 8 + (lid & 7)) * 128;
  const long n0 = (long)((xcd & 1) * 12 + (lid >> 3)) * 128;

  f32x4 acc[4][4];
#pragma unroll
  for (int i = 0; i < 4; ++i)
#pragma unroll
    for (int j = 0; j < 4; ++j) acc[i][j] = (f32x4){0.f, 0.f, 0.f, 0.f};

  const u16* ag = A + (m0 + w * 32 + (l >> 2)) * 1024 + (l & 3) * 8;
  const u16* bg = Bt + (n0 + w * 32 + (l >> 2)) * 1024 + (l & 3) * 8;
  u16* asl = As + w * 1024;
  u16* bsl = Bs + w * 1024;

  for (int kt = 0; kt < 32; ++kt) {
    const int ko = kt * 32;
    gld16(ag + ko, asl);
    gld16(ag + 16 * 1024 + ko, asl + 512);
    gld16(bg + ko, bsl);
    gld16(bg + 16 * 1024 + ko, bsl + 512);
    __syncthreads();
    bf16x8 af[4], bf[4];
#pragma unroll
    for (int mt = 0; mt < 4; ++mt)
      af[mt] = *(const bf16x8*)(As + (wr * 64 + mt * 16 + lanelo) * 32 + quad * 8);
#pragma unroll
    for (int nt = 0; nt < 4; ++nt)
      bf[nt] = *(const bf16x8*)(Bs + (wc * 64 + nt * 16 + lanelo) * 32 + quad * 8);
#pragma unroll
    for (int mt = 0; mt < 4; ++mt)
#pragma unroll
      for (int nt = 0; nt < 4; ++nt)
        acc[mt][nt] = __builtin_amdgcn_mfma_f32_16x16x32_bf16(af[mt], bf[nt], acc[mt][nt], 0, 0, 0);
    __syncthreads();
  }

  const int t = (int)(n0 >> 10);
  const float scl = (t == 0) ? 0.18033688011112042f : 1.0f;

  float bias_v[4];
#pragma unroll
  for (int nt = 0; nt < 4; ++nt) bias_v[nt] = bias[n0 + wc * 64 + nt * 16 + lanelo];

  u16* Ct = sm;  // [128][136]
#pragma unroll
  for (int mt = 0; mt < 4; ++mt)
#pragma unroll
    for (int nt = 0; nt < 4; ++nt)
#pragma unroll
      for (int r = 0; r < 4; ++r)
        Ct[(wr * 64 + mt * 16 + quad * 4 + r) * 136 + wc * 64 + nt * 16 + lanelo] =
            f2bf((acc[mt][nt][r] + bias_v[nt]) * scl);
  __syncthreads();

  const int b = (int)(m0 >> 11);
  const int s0 = (int)(m0 & 2047);
  const int h0 = (int)((n0 & 1023) >> 6);

  if (t < 2) {
    u16* dst = (t == 0) ? Qb : Kb;
#pragma unroll
    for (int p = 0; p < 8; ++p) {
      const int hh = p >> 2;
      const int sl = (p & 3) * 32 + (tid >> 3);
      const int c8 = tid & 7;
      us8 v = *(const us8*)(Ct + sl * 136 + hh * 64 + c8 * 8);
      const int pos = (c8 + sl) & 7;
      const size_t off = ((size_t)((b * 16 + h0 + hh) * 2048 + s0 + sl)) * 64 + pos * 8;
      *(us8*)(dst + off) = v;
    }
  } else {
#pragma unroll
    for (int p = 0; p < 8; ++p) {
      const int hh = p >> 2;
      const int dl = (p & 3) * 16 + (tid >> 4);
      const int c16 = tid & 15;
      us8 v;
#pragma unroll
      for (int j = 0; j < 8; ++j) v[j] = Ct[(c16 * 8 + j) * 136 + hh * 64 + dl];
      const int pos = (c16 + dl) & 15;
      const size_t off = ((size_t)((b * 16 + h0 + hh) * 64 + dl)) * 2048 + s0 + pos * 8;
      *(us8*)(Vtb + off) = v;
    }
  }
}

// ---------- flash attention: fused z-split, 512 threads ----------
// Wave-group z=tid>>8 handles keys [z*1024, z*1024+1024) with its own 32 KiB
// K/V slab (r6 inner loop verbatim; same swizzles, same barrier count,
// 2 blocks/CU x 8 waves = 16 waves/CU = r6 occupancy). Epilogue: z=1 writes
// f32 O-partials + rowsums to LDS (over dead Ks/Vs), one barrier, z=0 combines
// in-register, normalizes, writes final bf16 Ob. No combine kernel, no Op/lp.
__global__ __launch_bounds__(512, 4) void attn_kernel(
    const u16* __restrict__ Qb, const u16* __restrict__ Kb,
    const u16* __restrict__ Vtb, u16* __restrict__ Ob) {
  __shared__ u16 Ks[2][8192];   // per-z [key 128][dim 64]  8-chunk swizzled
  __shared__ u16 Vs[2][8192];   // per-z [dim 64][key 128] 16-chunk swizzled
  const int tid = threadIdx.x;
  const int w8 = tid >> 6;
  const int z = w8 >> 2, w = w8 & 3;   // z-group, wave within group
  const int l = tid & 63;
  const int m = l & 31, hi = l >> 5;
  const int fid = blockIdx.x;          // 0..511
  const int head = (fid & 7) + 8 * ((fid >> 3) & 3);   // 4 heads per XCD
  const int qt = fid >> 5;             // 0..15
  const u16* Qh = Qb + (size_t)head * 2048 * 64;
  const u16* Kh = Kb + (size_t)head * 2048 * 64;
  const u16* Vh = Vtb + (size_t)head * 64 * 2048;
  const int permaddr = (l ^ 32) << 2;

  // Q fragments (valid as B-operand: same per-lane layout)
  const int qrow = qt * 128 + w * 32 + m;
  bf16x8 qf[4];
#pragma unroll
  for (int ks = 0; ks < 4; ++ks) {
    const int pos = (ks * 2 + hi + qrow) & 7;
    qf[ks] = *(const bf16x8*)(Qh + (size_t)qrow * 64 + pos * 8);
  }

  f32x16 o0, o1;
#pragma unroll
  for (int i = 0; i < 16; ++i) { o0[i] = 0.f; o1[i] = 0.f; }
  float sacc = 0.f;

  for (int kt = 0; kt < 8; ++kt) {
    const int kb = z * 8 + kt;
    const u16* kbase = Kh + (size_t)kb * 8192;
#pragma unroll
    for (int j = 0; j < 4; ++j) {
      const int i = w * 4 + j;
      gld16(kbase + i * 512 + l * 8, &Ks[z][i * 512]);
    }
#pragma unroll
    for (int j = 0; j < 4; ++j) {
      const int i = w * 4 + j;
      const int dd = i * 4 + (l >> 4);
      gld16(Vh + (size_t)dd * 2048 + kb * 128 + (l & 15) * 8, &Vs[z][i * 512]);
    }
    __syncthreads();

#pragma unroll
    for (int g = 0; g < 4; ++g) {
      f32x16 st;
#pragma unroll
      for (int i = 0; i < 16; ++i) st[i] = 0.f;
      const int key = g * 32 + m;
#pragma unroll
      for (int ks = 0; ks < 4; ++ks) {
        const int pos = (ks * 2 + hi + key) & 7;
        bf16x8 kf = *(const bf16x8*)(&Ks[z][key * 64 + pos * 8]);
        st = __builtin_amdgcn_mfma_f32_32x32x16_bf16(kf, qf[ks], st, 0, 0, 0);
      }

      float p[16];
#pragma unroll
      for (int r = 0; r < 16; ++r) p[r] = fast_exp2(st[r]);
#pragma unroll
      for (int r = 0; r < 16; ++r) sacc += p[r];

      unsigned L[8];
#pragma unroll
      for (int q4 = 0; q4 < 4; ++q4) {
        L[2 * q4] = pkbf(p[4 * q4], p[4 * q4 + 1]);
        L[2 * q4 + 1] = pkbf(p[4 * q4 + 2], p[4 * q4 + 3]);
      }

#pragma unroll
      for (int s = 0; s < 2; ++s) {
        const unsigned a0 = L[4 * s], a1 = L[4 * s + 1];     // quad 2s
        const unsigned b0 = L[4 * s + 2], b1 = L[4 * s + 3]; // quad 2s+1
        const unsigned s0 = hi ? a0 : b0;
        const unsigned s1 = hi ? a1 : b1;
        const unsigned r0 = (unsigned)__builtin_amdgcn_ds_bpermute(permaddr, (int)s0);
        const unsigned r1 = (unsigned)__builtin_amdgcn_ds_bpermute(permaddr, (int)s1);
        int4 fd;
        fd.x = (int)(hi ? r0 : a0);
        fd.y = (int)(hi ? r1 : a1);
        fd.z = (int)(hi ? b0 : r0);
        fd.w = (int)(hi ? b1 : r1);
        union { int4 i; bf16x8 v; } pu; pu.i = fd;
        const int c = g * 4 + s * 2 + hi;   // key chunk for V B-operand
#pragma unroll
        for (int n = 0; n < 2; ++n) {
          const int d = n * 32 + m;
          const int pos = (c + d) & 15;
          bf16x8 vf = *(const bf16x8*)(&Vs[z][d * 128 + pos * 8]);
          if (n == 0) o0 = __builtin_amdgcn_mfma_f32_32x32x16_bf16(pu.v, vf, o0, 0, 0, 0);
          else        o1 = __builtin_amdgcn_mfma_f32_32x32x16_bf16(pu.v, vf, o1, 0, 0, 0);
        }
      }
    }
    __syncthreads();
  }

  // per-z row-sum: own half + partner half (defined on all 64 lanes)
  union { float f; int i; } sv; sv.f = sacc;
  union { float f; int i; } pv; pv.i = __builtin_amdgcn_ds_bpermute(permaddr, sv.i);
  const float ltot = sacc + pv.f;

  // ---- in-block z combine (Ks/Vs are dead after the final loop barrier) ----
  float* Osl = (float*)Ks;   // 4 waves x 32 rows x 64 dims f32 = 32 KiB (exact)
  float* Lz1 = (float*)Vs;   // 4 waves x 32 rowsums

  if (z == 1) {
    if (hi == 0) Lz1[w * 32 + m] = ltot;
#pragma unroll
    for (int r = 0; r < 16; ++r) {
      const int qlocal = (r & 3) + 8 * (r >> 2) + 4 * hi;
      Osl[w * 2048 + qlocal * 64 + m] = o0[r];
      Osl[w * 2048 + qlocal * 64 + 32 + m] = o1[r];
    }
  }
  __syncthreads();
  if (z == 0) {
    const float lfull = ltot + Lz1[w * 32 + m];
    union { float f; int i; } li; li.f = 1.0f / lfull;   // linv for q-row = m
    const int b = head >> 4, h = head & 15;
#pragma unroll
    for (int r = 0; r < 16; ++r) {
      const int qlocal = (r & 3) + 8 * (r >> 2) + 4 * hi;
      union { float f; int i; } lg;
      lg.i = __builtin_amdgcn_ds_bpermute(qlocal << 2, li.i);  // linv for this row
      const float v0 = (o0[r] + Osl[w * 2048 + qlocal * 64 + m]) * lg.f;
      const float v1 = (o1[r] + Osl[w * 2048 + qlocal * 64 + 32 + m]) * lg.f;
      const size_t base =
          ((size_t)(b * 2048 + qt * 128 + w * 32 + qlocal)) * 1024 + h * 64;
      Ob[base + m] = f2bf(v0);
      Ob[base + 32 + m] = f2bf(v1);
    }
  }
}

// ---------- proj GEMM: 128x64 tiles, 512 blocks (2/CU), plain stores ----------
__global__ __launch_bounds__(256) void proj_gemm_kernel(
    const u16* __restrict__ A, const u16* __restrict__ Bt,
    const float* __restrict__ bias, float* __restrict__ out) {
  __shared__ u16 sm[6144];   // As 128x32 (4096) + Bs 64x32 (2048)
  u16* As = sm;
  u16* Bs = sm + 4096;
  const int tid = threadIdx.x;
  const int w = tid >> 6, l = tid & 63, quad = l >> 4, lanelo = l & 15;
  const int wr = w >> 1, wc = w & 1;
  const int flat = blockIdx.x + 32 * blockIdx.y;       // 0..511
  const int xcd = flat & 7, lid = flat >> 3;
  const long m0 = (long)(xcd * 4 + (lid & 3)) * 128;
  const long n0 = (long)(lid >> 2) * 64;

  f32x4 acc[4][2];
#pragma unroll
  for (int i = 0; i < 4; ++i)
#pragma unroll
    for (int j = 0; j < 2; ++j) acc[i][j] = (f32x4){0.f, 0.f, 0.f, 0.f};

  const u16* ag = A + (m0 + w * 32 + (l >> 2)) * 1024 + (l & 3) * 8;
  const u16* bg = Bt + (n0 + w * 16 + (l >> 2)) * 1024 + (l & 3) * 8;
  u16* asl = As + w * 1024;
  u16* bsl = Bs + w * 512;

  for (int kt = 0; kt < 32; ++kt) {
    const int ko = kt * 32;
    gld16(ag + ko, asl);
    gld16(ag + 16 * 1024 + ko, asl + 512);
    gld16(bg + ko, bsl);
    __syncthreads();
    bf16x8 af[4], bf[2];
#pragma unroll
    for (int mt = 0; mt < 4; ++mt)
      af[mt] = *(const bf16x8*)(As + (wr * 64 + mt * 16 + lanelo) * 32 + quad * 8);
#pragma unroll
    for (int nt = 0; nt < 2; ++nt)
      bf[nt] = *(const bf16x8*)(Bs + (wc * 32 + nt * 16 + lanelo) * 32 + quad * 8);
#pragma unroll
    for (int mt = 0; mt < 4; ++mt)
#pragma unroll
      for (int nt = 0; nt < 2; ++nt)
        acc[mt][nt] = __builtin_amdgcn_mfma_f32_16x16x32_bf16(af[mt], bf[nt], acc[mt][nt], 0, 0, 0);
    __syncthreads();
  }

  float bias_v[2];
#pragma unroll
  for (int nt = 0; nt < 2; ++nt)
    bias_v[nt] = bias[n0 + wc * 32 + nt * 16 + lanelo];

#pragma unroll
  for (int mt = 0; mt < 4; ++mt)
#pragma unroll
    for (int nt = 0; nt < 2; ++nt)
#pragma unroll
      for (int r = 0; r < 4; ++r) {
        const size_t mm = m0 + wr * 64 + mt * 16 + quad * 4 + r;
        const size_t nn = n0 + wc * 32 + nt * 16 + lanelo;
        out[mm * 1024 + nn] = acc[mt][nt][r] + bias_v[nt];
      }
}

// ---------- launch ----------
extern "C" void kernel_launch(void* const* d_in, const int* in_sizes, int n_in,
                              void* d_out, int out_size, void* d_ws, size_t ws_size,
                              hipStream_t stream) {
  const float* x = (const float*)d_in[0];
  const float* Wqkv = (const float*)d_in[1];
  const float* bqkv = (const float*)d_in[2];
  const float* Wproj = (const float*)d_in[3];
  const float* bproj = (const float*)d_in[4];
  float* out = (float*)d_out;
  char* ws = (char*)d_ws;

  // workspace layout (42 MB), lifetime-based aliasing:
  //  [ 0..8M)   Xb (dead after qkv) -> Ob (attn out / proj in)
  //  [ 8..16M)  Wqkt ; [16..24M) Qb ; [24..32M) Kb ; [32..40M) Vtb ; [40..42M) Wpt
  u16* Xb   = (u16*)(ws);
  u16* Ob   = (u16*)(ws);
  u16* Wqkt = (u16*)(ws + 8388608);
  u16* Qb   = (u16*)(ws + 16777216);
  u16* Kb   = (u16*)(ws + 25165824);
  u16* Vtb  = (u16*)(ws + 33554432);
  u16* Wpt  = (u16*)(ws + 41943040);

  prep_kernel<<<8192, 256, 0, stream>>>(x, Xb, Wqkv, Wqkt, Wproj, Wpt);
  qkv_gemm_kernel<<<dim3(32, 24), 256, 0, stream>>>(Xb, Wqkt, bqkv, Qb, Kb, Vtb);
  attn_kernel<<<512, 512, 0, stream>>>(Qb, Kb, Vtb, Ob);
  proj_gemm_kernel<<<dim3(32, 16), 256, 0, stream>>>(Ob, Wpt, bproj, out);
}